// Round 5
// baseline (615.620 us; speedup 1.0000x reference)
//
#include <hip/hip_runtime.h>
#include <hip/hip_bf16.h>
#include <cstdint>

typedef __attribute__((ext_vector_type(4))) float f32x4;
typedef __attribute__((ext_vector_type(8))) short bf16x8;

__device__ inline unsigned short f2bf(float f) {
    union { float f; unsigned u; } v; v.f = f;
    unsigned r = v.u + 0x7FFFu + ((v.u >> 16) & 1u);
    return (unsigned short)(r >> 16);
}
__device__ inline float bf2f(unsigned short h) {
    union { unsigned u; float f; } v; v.u = ((unsigned)h) << 16;
    return v.f;
}

// ---------------------------------------------------------------- prep
// WuT/WvT: [256][64] = [Wl(64) | Wa(128) | WV(32) | Ww_firsthalf(32)] (c-major)
// WeXf/WeXb: [96][64] = [We(64) | Ww_secondhalf(32)]
__global__ void prep_kernel(
    const float* __restrict__ We,
    const float* __restrict__ Wul, const float* __restrict__ Wau, const float* __restrict__ WVu,
    const float* __restrict__ Wvl, const float* __restrict__ Wav, const float* __restrict__ WVv,
    const float* __restrict__ Wwu, const float* __restrict__ Wwv,
    const float* __restrict__ bul, const float* __restrict__ bau, const float* __restrict__ bVu,
    const float* __restrict__ bvl, const float* __restrict__ bav, const float* __restrict__ bVv,
    unsigned short* __restrict__ WeXf, unsigned short* __restrict__ WeXb,
    unsigned short* __restrict__ WuT, unsigned short* __restrict__ WvT,
    float* __restrict__ bcu, float* __restrict__ bcv)
{
    int tid0 = blockIdx.x * blockDim.x + threadIdx.x;
    int stride = gridDim.x * blockDim.x;
    for (int i = tid0; i < 96 * 64; i += stride) {
        int c = i >> 6, k = i & 63;
        WeXf[i] = f2bf((c < 64) ? We[k * 64 + c] : Wwv[(64 + k) * 32 + (c - 64)]);
        WeXb[i] = f2bf((c < 64) ? We[k * 64 + c] : Wwu[(64 + k) * 32 + (c - 64)]);
    }
    for (int i = tid0; i < 256 * 64; i += stride) {
        int c = i >> 6, k = i & 63;
        float vu, vv;
        if (c < 64)       { vu = Wul[k * 64 + c];          vv = Wvl[k * 64 + c]; }
        else if (c < 192) { vu = Wau[k * 128 + (c - 64)];  vv = Wav[k * 128 + (c - 64)]; }
        else if (c < 224) { vu = WVu[k * 32 + (c - 192)];  vv = WVv[k * 32 + (c - 192)]; }
        else              { vu = Wwv[k * 32 + (c - 224)];  vv = Wwu[k * 32 + (c - 224)]; }
        WuT[i] = f2bf(vu);
        WvT[i] = f2bf(vv);
    }
    for (int i = tid0; i < 224; i += stride) {
        bcu[i] = (i < 64) ? bul[i] : (i < 192) ? bau[i - 64] : bVu[i - 192];
        bcv[i] = (i < 64) ? bvl[i] : (i < 192) ? bav[i - 64] : bVv[i - 192];
    }
}

// ---------------------------------------------------------------- node pre:
// [64 nodes/block] feat@[Wl|Wa|WV|Ww1] (K=64, N=256)
// -> he(bf16), att(bf16), outV(f32 cols 0..31 of out), proj(f32 32);
// also zeroes agg32/ws for this node range.
__global__ __launch_bounds__(256) void node_pre_kernel(
    const float* __restrict__ feat, int N,
    const unsigned short* __restrict__ WT,   // [256][64] bf16 (c-major)
    const float* __restrict__ bcat,          // [224]
    unsigned short* __restrict__ he,         // [N][64]  bf16
    unsigned short* __restrict__ att,        // [N][128] bf16
    float* __restrict__ outV,                // out rows stride 64, cols 0..31
    float* __restrict__ proj,                // [N][32] f32
    float* __restrict__ agg32,               // [N][32] f32 (zeroed here)
    float* __restrict__ ws)                  // [N] (zeroed here)
{
    __shared__ unsigned short lA[64 * 64];
    __shared__ unsigned short lW[256 * 64];
    int tid = threadIdx.x;
    int n0 = blockIdx.x * 64;

    const uint4* wsrc = (const uint4*)WT;
    for (int i = tid; i < 256 * 8; i += 256) {
        int r = i >> 3, ch = i & 7;
        *(uint4*)&lW[r * 64 + ((ch ^ (r & 7)) << 3)] = wsrc[i];
    }
    #pragma unroll
    for (int j = 0; j < 4; ++j) {
        int fi = j * 1024 + tid * 4;
        int r = fi >> 6, k = fi & 63;
        int n = n0 + r;
        float4 v = make_float4(0.f, 0.f, 0.f, 0.f);
        if (n < N) v = *(const float4*)&feat[(size_t)n * 64 + k];
        uint2 pk;
        pk.x = (unsigned)f2bf(v.x) | ((unsigned)f2bf(v.y) << 16);
        pk.y = (unsigned)f2bf(v.z) | ((unsigned)f2bf(v.w) << 16);
        *(uint2*)&lA[r * 64 + (((k >> 3) ^ (r & 7)) << 3) + (k & 7)] = pk;
    }
    {   // zero agg32 + ws
        for (int i = tid; i < 64 * 32; i += 256) {
            int n = n0 + (i >> 5);
            if (n < N) agg32[(size_t)n * 32 + (i & 31)] = 0.f;
        }
        if (tid < 64) { int n = n0 + tid; if (n < N) ws[n] = 0.f; }
    }
    __syncthreads();

    int wv = tid >> 6, lane = tid & 63;
    int r0 = wv * 16;
    int lrow = lane & 15, lkg = lane >> 4;
    int rr = r0 + lrow;

    bf16x8 a[2];
    #pragma unroll
    for (int h = 0; h < 2; ++h) {
        int ch = h * 4 + lkg;
        a[h] = *(const bf16x8*)&lA[rr * 64 + ((ch ^ (rr & 7)) << 3)];
    }
    f32x4 acc[16];
    #pragma unroll
    for (int t = 0; t < 16; ++t) acc[t] = (f32x4){0.f, 0.f, 0.f, 0.f};
    #pragma unroll
    for (int t = 0; t < 16; ++t) {
        int row = t * 16 + lrow;
        #pragma unroll
        for (int h = 0; h < 2; ++h) {
            int ch = h * 4 + lkg;
            bf16x8 b = *(const bf16x8*)&lW[row * 64 + ((ch ^ (row & 7)) << 3)];
            acc[t] = __builtin_amdgcn_mfma_f32_16x16x32_bf16(a[h], b, acc[t], 0, 0, 0);
        }
    }
    #pragma unroll
    for (int t = 0; t < 16; ++t) {
        #pragma unroll
        for (int q = 0; q < 4; ++q) {
            int n = n0 + r0 + lkg * 4 + q;
            if (n >= N) continue;
            int c = t * 16 + lrow;
            float raw = acc[t][q];
            if (t < 4)       he[(size_t)n * 64 + c] = f2bf(raw + bcat[c]);
            else if (t < 12) att[(size_t)n * 128 + (c - 64)] = f2bf(raw + bcat[c]);
            else if (t < 14) outV[(size_t)n * 64 + (c - 192)] = raw + bcat[c];
            else             proj[(size_t)n * 32 + (c - 224)] = raw;   // no bias
        }
    }
}

// ---------------------------------------------------------------- edge:
// [64 edges/block] GEMM e@[We|Ww2] (K=64, N=96).
// Phase-split ILP epilogue:
//  score: w=exp(<[src_feat|e],att_dst>)  (a2 from LDS A-tile, 8-edge batches)
//  atomic: agg32[dst] += w*(proj_src[src]+proj2); ws[dst] += w
//  store: out_he = GEMM + be + he_src[src] + he_dst[dst]
__global__ __launch_bounds__(256) void edge_kernel(
    const float* __restrict__ efeat, int E,
    const int* __restrict__ src, const int* __restrict__ dst,
    const float* __restrict__ src_feat,
    const float* __restrict__ proj_src,      // [Nsrc][32] f32
    const unsigned short* __restrict__ he_src, const unsigned short* __restrict__ he_dst,
    const unsigned short* __restrict__ att_dst,
    const unsigned short* __restrict__ WeX,  // [96][64] bf16 (c-major)
    const float* __restrict__ be,
    float* __restrict__ out_he,
    float* __restrict__ agg32, float* __restrict__ wsum)
{
    // 32 KB: lA[0..8K) preserved through epilogue; lW[8K..20K); sAcc f32[64][96] at [8K..32K)
    __shared__ __align__(16) char smem[32768];
    unsigned short* lA = (unsigned short*)smem;
    unsigned short* lW = (unsigned short*)(smem + 8192);
    float* sAcc = (float*)(smem + 8192);

    int tid = threadIdx.x;
    int e0 = blockIdx.x * 64;
    int lane = tid & 63;
    int wvu = __builtin_amdgcn_readfirstlane(tid >> 6);
    int eBase = e0 + wvu * 16;

    // hoist edge indices: wave-uniform -> scalar loads, issued before GEMM
    int si_[16], di_[16];
    #pragma unroll
    for (int q = 0; q < 16; ++q) {
        int e = eBase + q;
        si_[q] = (e < E) ? src[e] : 0;
        di_[q] = (e < E) ? dst[e] : 0;
    }

    const uint4* wsrc = (const uint4*)WeX;
    for (int i = tid; i < 96 * 8; i += 256) {
        int r = i >> 3, ch = i & 7;
        *(uint4*)&lW[r * 64 + ((ch ^ (r & 7)) << 3)] = wsrc[i];
    }
    #pragma unroll
    for (int j = 0; j < 4; ++j) {
        int fi = j * 1024 + tid * 4;
        int r = fi >> 6, k = fi & 63;
        int e = e0 + r;
        float4 v = make_float4(0.f, 0.f, 0.f, 0.f);
        if (e < E) v = *(const float4*)&efeat[(size_t)e * 64 + k];
        uint2 pk;
        pk.x = (unsigned)f2bf(v.x) | ((unsigned)f2bf(v.y) << 16);
        pk.y = (unsigned)f2bf(v.z) | ((unsigned)f2bf(v.w) << 16);
        *(uint2*)&lA[r * 64 + (((k >> 3) ^ (r & 7)) << 3) + (k & 7)] = pk;
    }
    __syncthreads();

    int r0 = wvu * 16;
    int lrow = lane & 15, lkg = lane >> 4;
    int rr = r0 + lrow;

    bf16x8 a[2];
    #pragma unroll
    for (int h = 0; h < 2; ++h) {
        int ch = h * 4 + lkg;
        a[h] = *(const bf16x8*)&lA[rr * 64 + ((ch ^ (rr & 7)) << 3)];
    }
    f32x4 acc[6];
    #pragma unroll
    for (int t = 0; t < 6; ++t) acc[t] = (f32x4){0.f, 0.f, 0.f, 0.f};
    #pragma unroll
    for (int t = 0; t < 6; ++t) {
        int row = t * 16 + lrow;
        #pragma unroll
        for (int h = 0; h < 2; ++h) {
            int ch = h * 4 + lkg;
            bf16x8 b = *(const bf16x8*)&lW[row * 64 + ((ch ^ (row & 7)) << 3)];
            acc[t] = __builtin_amdgcn_mfma_f32_16x16x32_bf16(a[h], b, acc[t], 0, 0, 0);
        }
    }
    __syncthreads();   // all waves done reading lW (lA stays live)
    #pragma unroll
    for (int t = 0; t < 6; ++t) {
        int c = t * 16 + lrow;
        float bb = (c < 64) ? be[c] : 0.f;
        #pragma unroll
        for (int q = 0; q < 4; ++q) {
            int r = r0 + lkg * 4 + q;
            sAcc[r * 96 + c] = acc[t][q] + bb;
        }
    }
    __syncthreads();

    // ---- score phase: 8-edge batches, butterflies interleaved for ILP
    float w_[16];
    #pragma unroll
    for (int half = 0; half < 2; ++half) {
        float p[8];
        #pragma unroll
        for (int q = 0; q < 8; ++q) {
            int qq = half * 8 + q;
            int rloc = r0 + qq;
            float a2 = bf2f(lA[rloc * 64 + (((lane >> 3) ^ (rloc & 7)) << 3) + (lane & 7)]);
            int e = eBase + qq;
            float a1 = 0.f, t1 = 0.f, t2 = 0.f;
            if (e < E) {
                int si = si_[qq], di = di_[qq];
                a1 = src_feat[(size_t)si * 64 + lane];
                t1 = bf2f(att_dst[(size_t)di * 128 + lane]);
                t2 = bf2f(att_dst[(size_t)di * 128 + 64 + lane]);
            }
            p[q] = a1 * t1 + a2 * t2;
        }
        #pragma unroll
        for (int o = 32; o > 0; o >>= 1) {
            #pragma unroll
            for (int q = 0; q < 8; ++q) p[q] += __shfl_xor(p[q], o, 64);
        }
        #pragma unroll
        for (int q = 0; q < 8; ++q) w_[half * 8 + q] = __expf(p[q]);
    }

    // ---- atomic scatter phase
    #pragma unroll
    for (int q = 0; q < 16; ++q) {
        int e = eBase + q;
        if (e >= E) continue;
        float w = w_[q];
        if (lane < 32) {
            float pv = proj_src[(size_t)si_[q] * 32 + lane] + sAcc[(r0 + q) * 96 + 64 + lane];
            unsafeAtomicAdd(&agg32[(size_t)di_[q] * 32 + lane], w * pv);
        } else if (lane == 32) {
            unsafeAtomicAdd(&wsum[di_[q]], w);
        }
    }

    // ---- out_he store phase (coalesced rows)
    #pragma unroll
    for (int q = 0; q < 16; ++q) {
        int e = eBase + q;
        if (e >= E) continue;
        float hs = bf2f(he_src[(size_t)si_[q] * 64 + lane]);
        float hd = bf2f(he_dst[(size_t)di_[q] * 64 + lane]);
        out_he[(size_t)e * 64 + lane] = sAcc[(r0 + q) * 96 + lane] + hs + hd;
    }
}

// ---------------------------------------------------------------- finalize:
// out[n][32+c] = agg32[n][c]/ws[n] + bias[c]   (ws==0 -> bias)
__global__ void finalize_kernel(const float* __restrict__ agg32, const float* __restrict__ ws,
                                int N, const float* __restrict__ bias,
                                float* __restrict__ outp)
{
    int idx = blockIdx.x * blockDim.x + threadIdx.x;
    if (idx >= N * 32) return;
    int n = idx >> 5, c = idx & 31;
    float s = ws[n];
    float sc = (s > 0.f) ? 1.0f / s : 0.f;
    outp[(size_t)n * 64 + 32 + c] = agg32[idx] * sc + bias[c];
}

// ---------------------------------------------------------------- launch
extern "C" void kernel_launch(void* const* d_in, const int* in_sizes, int n_in,
                              void* d_out, int out_size, void* d_ws, size_t ws_size,
                              hipStream_t stream)
{
    const float* f_feat = (const float*)d_in[0];
    const float* b_feat = (const float*)d_in[1];
    const float* u_feat = (const float*)d_in[2];
    const float* v_feat = (const float*)d_in[3];
    const int* fsrc = (const int*)d_in[4];
    const int* fdst = (const int*)d_in[5];
    const int* bsrc = (const int*)d_in[6];
    const int* bdst = (const int*)d_in[7];
    const float* We  = (const float*)d_in[8];
    const float* be  = (const float*)d_in[9];
    const float* Wul = (const float*)d_in[10];
    const float* bul = (const float*)d_in[11];
    const float* Wvl = (const float*)d_in[12];
    const float* bvl = (const float*)d_in[13];
    const float* Wau = (const float*)d_in[14];
    const float* bau = (const float*)d_in[15];
    const float* Wav = (const float*)d_in[16];
    const float* bav = (const float*)d_in[17];
    const float* Wwu = (const float*)d_in[18];
    const float* bwu = (const float*)d_in[19];
    const float* Wwv = (const float*)d_in[20];
    const float* bwv = (const float*)d_in[21];
    const float* WVu = (const float*)d_in[22];
    const float* bVu = (const float*)d_in[23];
    const float* WVv = (const float*)d_in[24];
    const float* bVv = (const float*)d_in[25];

    int EF = in_sizes[0] / 64;
    int EB = in_sizes[1] / 64;
    int NU = in_sizes[2] / 64;
    int NV = in_sizes[3] / 64;

    float* out = (float*)d_out;
    float* hf = out;
    float* hb = hf + (size_t)EF * 64;
    float* hu = hb + (size_t)EB * 64;
    float* hv = hu + (size_t)NU * 64;

    char* wp = (char*)d_ws;
    auto alloc = [&](size_t bytes) { char* p = wp; wp += (bytes + 255) & ~(size_t)255; return p; };
    unsigned short* he_u  = (unsigned short*)alloc((size_t)NU * 64 * 2);
    unsigned short* he_v  = (unsigned short*)alloc((size_t)NV * 64 * 2);
    unsigned short* att_u = (unsigned short*)alloc((size_t)NU * 128 * 2);
    unsigned short* att_v = (unsigned short*)alloc((size_t)NV * 128 * 2);
    float* proj_u = (float*)alloc((size_t)NU * 32 * 4);
    float* proj_v = (float*)alloc((size_t)NV * 32 * 4);
    float* agg_u  = (float*)alloc((size_t)NU * 32 * 4);
    float* agg_v  = (float*)alloc((size_t)NV * 32 * 4);
    float* ws_u   = (float*)alloc((size_t)NU * 4);
    float* ws_v   = (float*)alloc((size_t)NV * 4);
    unsigned short* WeXf = (unsigned short*)alloc(96 * 64 * 2);
    unsigned short* WeXb = (unsigned short*)alloc(96 * 64 * 2);
    unsigned short* WuT  = (unsigned short*)alloc(256 * 64 * 2);
    unsigned short* WvT  = (unsigned short*)alloc(256 * 64 * 2);
    float* bcu = (float*)alloc(224 * 4);
    float* bcv = (float*)alloc(224 * 4);

    prep_kernel<<<64, 256, 0, stream>>>(We, Wul, Wau, WVu, Wvl, Wav, WVv, Wwu, Wwv,
                                        bul, bau, bVu, bvl, bav, bVv,
                                        WeXf, WeXb, WuT, WvT, bcu, bcv);

    node_pre_kernel<<<(NU + 63) / 64, 256, 0, stream>>>(u_feat, NU, WuT, bcu,
                                                        he_u, att_u, hu, proj_u, agg_u, ws_u);
    node_pre_kernel<<<(NV + 63) / 64, 256, 0, stream>>>(v_feat, NV, WvT, bcv,
                                                        he_v, att_v, hv, proj_v, agg_v, ws_v);

    edge_kernel<<<(EF + 63) / 64, 256, 0, stream>>>(f_feat, EF, fsrc, fdst, u_feat, proj_u,
                                                    he_u, he_v, att_v, WeXf, be, hf, agg_v, ws_v);
    edge_kernel<<<(EB + 63) / 64, 256, 0, stream>>>(b_feat, EB, bsrc, bdst, v_feat, proj_v,
                                                    he_v, he_u, att_u, WeXb, be, hb, agg_u, ws_u);

    finalize_kernel<<<(NU * 32 + 255) / 256, 256, 0, stream>>>(agg_u, ws_u, NU, bwu, hu);
    finalize_kernel<<<(NV * 32 + 255) / 256, 256, 0, stream>>>(agg_v, ws_v, NV, bwv, hv);
}

// Round 7
// 496.870 us; speedup vs baseline: 1.2390x; 1.2390x over previous
//
#include <hip/hip_runtime.h>
#include <hip/hip_bf16.h>
#include <cstdint>

typedef __attribute__((ext_vector_type(4))) float f32x4;
typedef __attribute__((ext_vector_type(8))) short bf16x8;

__device__ inline unsigned short f2bf(float f) {
    union { float f; unsigned u; } v; v.f = f;
    unsigned r = v.u + 0x7FFFu + ((v.u >> 16) & 1u);
    return (unsigned short)(r >> 16);
}
__device__ inline float bf2f(unsigned short h) {
    union { unsigned u; float f; } v; v.u = ((unsigned)h) << 16;
    return v.f;
}

// ---------------------------------------------------------------- prep
__global__ void prep_kernel(
    const float* __restrict__ We,
    const float* __restrict__ Wul, const float* __restrict__ Wau, const float* __restrict__ WVu,
    const float* __restrict__ Wvl, const float* __restrict__ Wav, const float* __restrict__ WVv,
    const float* __restrict__ Wwu, const float* __restrict__ Wwv,
    const float* __restrict__ bul, const float* __restrict__ bau, const float* __restrict__ bVu,
    const float* __restrict__ bvl, const float* __restrict__ bav, const float* __restrict__ bVv,
    unsigned short* __restrict__ WeXf, unsigned short* __restrict__ WeXb,
    unsigned short* __restrict__ WuT, unsigned short* __restrict__ WvT,
    float* __restrict__ bcu, float* __restrict__ bcv)
{
    int tid0 = blockIdx.x * blockDim.x + threadIdx.x;
    int stride = gridDim.x * blockDim.x;
    for (int i = tid0; i < 96 * 64; i += stride) {
        int c = i >> 6, k = i & 63;
        WeXf[i] = f2bf((c < 64) ? We[k * 64 + c] : Wwv[(64 + k) * 32 + (c - 64)]);
        WeXb[i] = f2bf((c < 64) ? We[k * 64 + c] : Wwu[(64 + k) * 32 + (c - 64)]);
    }
    for (int i = tid0; i < 256 * 64; i += stride) {
        int c = i >> 6, k = i & 63;
        float vu, vv;
        if (c < 64)       { vu = Wul[k * 64 + c];          vv = Wvl[k * 64 + c]; }
        else if (c < 192) { vu = Wau[k * 128 + (c - 64)];  vv = Wav[k * 128 + (c - 64)]; }
        else if (c < 224) { vu = WVu[k * 32 + (c - 192)];  vv = WVv[k * 32 + (c - 192)]; }
        else              { vu = Wwv[k * 32 + (c - 224)];  vv = Wwu[k * 32 + (c - 224)]; }
        WuT[i] = f2bf(vu);
        WvT[i] = f2bf(vv);
    }
    for (int i = tid0; i < 224; i += stride) {
        bcu[i] = (i < 64) ? bul[i] : (i < 192) ? bau[i - 64] : bVu[i - 192];
        bcv[i] = (i < 64) ? bvl[i] : (i < 192) ? bav[i - 64] : bVv[i - 192];
    }
}

// ---------------------------------------------------------------- node pre:
// [64 nodes/block] feat@[Wl|Wa|WV|Ww1] (K=64, N=256)
// -> he(bf16), att_p(packed u32 pairs), ubf(bf16 raw feat), outV, proj(f32 32);
// zeroes agg32/ws.
__global__ __launch_bounds__(256) void node_pre_kernel(
    const float* __restrict__ feat, int N,
    const unsigned short* __restrict__ WT,   // [256][64] bf16 (c-major)
    const float* __restrict__ bcat,          // [224]
    unsigned short* __restrict__ he,         // [N][64]  bf16
    unsigned* __restrict__ att_p,            // [N][64]  u32 = (att1[c], att2[c]) bf16 pair
    unsigned short* __restrict__ ubf,        // [N][64]  bf16 copy of feat
    float* __restrict__ outV,                // out rows stride 64, cols 0..31
    float* __restrict__ proj,                // [N][32] f32
    float* __restrict__ agg32,               // [N][32] f32 (zeroed here)
    float* __restrict__ ws)                  // [N] (zeroed here)
{
    __shared__ unsigned short lA[64 * 64];
    __shared__ unsigned short lW[256 * 64];
    int tid = threadIdx.x;
    int n0 = blockIdx.x * 64;

    const uint4* wsrc = (const uint4*)WT;
    for (int i = tid; i < 256 * 8; i += 256) {
        int r = i >> 3, ch = i & 7;
        *(uint4*)&lW[r * 64 + ((ch ^ (r & 7)) << 3)] = wsrc[i];
    }
    #pragma unroll
    for (int j = 0; j < 4; ++j) {
        int fi = j * 1024 + tid * 4;
        int r = fi >> 6, k = fi & 63;
        int n = n0 + r;
        f32x4 v = (f32x4){0.f, 0.f, 0.f, 0.f};
        if (n < N) v = __builtin_nontemporal_load((const f32x4*)&feat[(size_t)n * 64 + k]);
        uint2 pk;
        pk.x = (unsigned)f2bf(v.x) | ((unsigned)f2bf(v.y) << 16);
        pk.y = (unsigned)f2bf(v.z) | ((unsigned)f2bf(v.w) << 16);
        *(uint2*)&lA[r * 64 + (((k >> 3) ^ (r & 7)) << 3) + (k & 7)] = pk;
        if (n < N) *(uint2*)&ubf[(size_t)n * 64 + k] = pk;   // raw bf16 feat table
    }
    {   // zero agg32 + ws
        for (int i = tid; i < 64 * 32; i += 256) {
            int n = n0 + (i >> 5);
            if (n < N) agg32[(size_t)n * 32 + (i & 31)] = 0.f;
        }
        if (tid < 64) { int n = n0 + tid; if (n < N) ws[n] = 0.f; }
    }
    __syncthreads();

    int wv = tid >> 6, lane = tid & 63;
    int r0 = wv * 16;
    int lrow = lane & 15, lkg = lane >> 4;
    int rr = r0 + lrow;

    bf16x8 a[2];
    #pragma unroll
    for (int h = 0; h < 2; ++h) {
        int ch = h * 4 + lkg;
        a[h] = *(const bf16x8*)&lA[rr * 64 + ((ch ^ (rr & 7)) << 3)];
    }
    f32x4 acc[16];
    #pragma unroll
    for (int t = 0; t < 16; ++t) acc[t] = (f32x4){0.f, 0.f, 0.f, 0.f};
    #pragma unroll
    for (int t = 0; t < 16; ++t) {
        int row = t * 16 + lrow;
        #pragma unroll
        for (int h = 0; h < 2; ++h) {
            int ch = h * 4 + lkg;
            bf16x8 b = *(const bf16x8*)&lW[row * 64 + ((ch ^ (row & 7)) << 3)];
            acc[t] = __builtin_amdgcn_mfma_f32_16x16x32_bf16(a[h], b, acc[t], 0, 0, 0);
        }
    }
    unsigned short* att16 = (unsigned short*)att_p;
    #pragma unroll
    for (int t = 0; t < 16; ++t) {
        #pragma unroll
        for (int q = 0; q < 4; ++q) {
            int n = n0 + r0 + lkg * 4 + q;
            if (n >= N) continue;
            int c = t * 16 + lrow;
            float raw = acc[t][q];
            if (t < 4) {
                he[(size_t)n * 64 + c] = f2bf(raw + bcat[c]);
            } else if (t < 12) {
                int cc = c - 64;                     // 0..127
                int idx = cc & 63, half = cc >> 6;   // pair-slot, member
                att16[(size_t)n * 128 + idx * 2 + half] = f2bf(raw + bcat[c]);
            } else if (t < 14) {
                __builtin_nontemporal_store(raw + bcat[c], &outV[(size_t)n * 64 + (c - 192)]);
            } else {
                proj[(size_t)n * 32 + (c - 224)] = raw;   // no bias
            }
        }
    }
}

// ---------------------------------------------------------------- edge:
// [64 edges/block] GEMM e@[We|Ww2] (K=64, N=96).
// score: w=exp(<[ubf_src|e],att_dst>)  (packed att, bf16 a1)
// store: out_he = GEMM + be + he_src + he_dst  (nontemporal)
// atomic: agg32[dst] += w*(proj_src+proj2); ws[dst] += w
__global__ __launch_bounds__(256) void edge_kernel(
    const float* __restrict__ efeat, int E,
    const int* __restrict__ src, const int* __restrict__ dst,
    const unsigned short* __restrict__ ubf_src,  // [Nsrc][64] bf16
    const float* __restrict__ proj_src,          // [Nsrc][32] f32
    const unsigned short* __restrict__ he_src, const unsigned short* __restrict__ he_dst,
    const unsigned* __restrict__ att_dst,        // [Ndst][64] packed
    const unsigned short* __restrict__ WeX,      // [96][64] bf16 (c-major)
    const float* __restrict__ be,
    float* __restrict__ out_he,
    float* __restrict__ agg32, float* __restrict__ wsum)
{
    // 24 KB: lA(8K)+lW(12K) during MFMA; whole buffer reused as sAcc f32[64][96]
    __shared__ __align__(16) char smem[24576];
    unsigned short* lA = (unsigned short*)smem;
    unsigned short* lW = (unsigned short*)(smem + 8192);
    float* sAcc = (float*)smem;

    int tid = threadIdx.x;
    int e0 = blockIdx.x * 64;
    int lane = tid & 63;
    int wvu = __builtin_amdgcn_readfirstlane(tid >> 6);
    int eBase = e0 + wvu * 16;

    // wave-uniform edge indices -> scalar loads before GEMM
    int si_[16], di_[16];
    #pragma unroll
    for (int q = 0; q < 16; ++q) {
        int e = eBase + q;
        si_[q] = (e < E) ? src[e] : 0;
        di_[q] = (e < E) ? dst[e] : 0;
    }

    const uint4* wsrc = (const uint4*)WeX;
    for (int i = tid; i < 96 * 8; i += 256) {
        int r = i >> 3, ch = i & 7;
        *(uint4*)&lW[r * 64 + ((ch ^ (r & 7)) << 3)] = wsrc[i];
    }
    #pragma unroll
    for (int j = 0; j < 4; ++j) {
        int fi = j * 1024 + tid * 4;
        int r = fi >> 6, k = fi & 63;
        int e = e0 + r;
        float4 v = make_float4(0.f, 0.f, 0.f, 0.f);
        if (e < E) v = *(const float4*)&efeat[(size_t)e * 64 + k];
        uint2 pk;
        pk.x = (unsigned)f2bf(v.x) | ((unsigned)f2bf(v.y) << 16);
        pk.y = (unsigned)f2bf(v.z) | ((unsigned)f2bf(v.w) << 16);
        *(uint2*)&lA[r * 64 + (((k >> 3) ^ (r & 7)) << 3) + (k & 7)] = pk;
    }
    __syncthreads();

    int r0 = wvu * 16;
    int lrow = lane & 15, lkg = lane >> 4;
    int rr = r0 + lrow;

    bf16x8 a[2];
    #pragma unroll
    for (int h = 0; h < 2; ++h) {
        int ch = h * 4 + lkg;
        a[h] = *(const bf16x8*)&lA[rr * 64 + ((ch ^ (rr & 7)) << 3)];
    }
    f32x4 acc[6];
    #pragma unroll
    for (int t = 0; t < 6; ++t) acc[t] = (f32x4){0.f, 0.f, 0.f, 0.f};
    #pragma unroll
    for (int t = 0; t < 6; ++t) {
        int row = t * 16 + lrow;
        #pragma unroll
        for (int h = 0; h < 2; ++h) {
            int ch = h * 4 + lkg;
            bf16x8 b = *(const bf16x8*)&lW[row * 64 + ((ch ^ (row & 7)) << 3)];
            acc[t] = __builtin_amdgcn_mfma_f32_16x16x32_bf16(a[h], b, acc[t], 0, 0, 0);
        }
    }
    __syncthreads();   // all waves done reading lA/lW
    #pragma unroll
    for (int t = 0; t < 6; ++t) {
        int c = t * 16 + lrow;
        float bb = (c < 64) ? be[c] : 0.f;
        #pragma unroll
        for (int q = 0; q < 4; ++q) {
            int r = r0 + lkg * 4 + q;
            sAcc[r * 96 + c] = acc[t][q] + bb;
        }
    }
    __syncthreads();

    // ---- score phase: 8-edge batches, butterflies interleaved for ILP
    float w_[16];
    #pragma unroll
    for (int half = 0; half < 2; ++half) {
        float p[8];
        #pragma unroll
        for (int q = 0; q < 8; ++q) {
            int qq = half * 8 + q;
            int e = eBase + qq;
            float a1 = 0.f, a2 = 0.f, t1 = 0.f, t2 = 0.f;
            if (e < E) {
                int si = si_[qq], di = di_[qq];
                a1 = bf2f(ubf_src[(size_t)si * 64 + lane]);
                unsigned tw = att_dst[(size_t)di * 64 + lane];
                t1 = bf2f((unsigned short)(tw & 0xFFFF));
                t2 = bf2f((unsigned short)(tw >> 16));
                a2 = efeat[(size_t)e * 64 + lane];
            }
            p[q] = a1 * t1 + a2 * t2;
        }
        #pragma unroll
        for (int o = 32; o > 0; o >>= 1) {
            #pragma unroll
            for (int q = 0; q < 8; ++q) p[q] += __shfl_xor(p[q], o, 64);
        }
        #pragma unroll
        for (int q = 0; q < 8; ++q) w_[half * 8 + q] = __expf(p[q]);
    }

    // ---- out_he store phase (coalesced rows, nontemporal)
    #pragma unroll
    for (int q = 0; q < 16; ++q) {
        int e = eBase + q;
        if (e >= E) continue;
        float hs = bf2f(he_src[(size_t)si_[q] * 64 + lane]);
        float hd = bf2f(he_dst[(size_t)di_[q] * 64 + lane]);
        __builtin_nontemporal_store(sAcc[(r0 + q) * 96 + lane] + hs + hd,
                                    &out_he[(size_t)e * 64 + lane]);
    }

    // ---- atomic scatter phase
    #pragma unroll
    for (int q = 0; q < 16; ++q) {
        int e = eBase + q;
        if (e >= E) continue;
        float w = w_[q];
        if (lane < 32) {
            float pv = proj_src[(size_t)si_[q] * 32 + lane] + sAcc[(r0 + q) * 96 + 64 + lane];
            unsafeAtomicAdd(&agg32[(size_t)di_[q] * 32 + lane], w * pv);
        } else if (lane == 32) {
            unsafeAtomicAdd(&wsum[di_[q]], w);
        }
    }
}

// ---------------------------------------------------------------- finalize:
// out[n][32+c] = agg32[n][c]/ws[n] + bias[c]   (ws==0 -> bias)
__global__ void finalize_kernel(const float* __restrict__ agg32, const float* __restrict__ ws,
                                int N, const float* __restrict__ bias,
                                float* __restrict__ outp)
{
    int idx = blockIdx.x * blockDim.x + threadIdx.x;
    if (idx >= N * 32) return;
    int n = idx >> 5, c = idx & 31;
    float s = ws[n];
    float sc = (s > 0.f) ? 1.0f / s : 0.f;
    __builtin_nontemporal_store(agg32[idx] * sc + bias[c], &outp[(size_t)n * 64 + 32 + c]);
}

// ---------------------------------------------------------------- launch
extern "C" void kernel_launch(void* const* d_in, const int* in_sizes, int n_in,
                              void* d_out, int out_size, void* d_ws, size_t ws_size,
                              hipStream_t stream)
{
    const float* f_feat = (const float*)d_in[0];
    const float* b_feat = (const float*)d_in[1];
    const float* u_feat = (const float*)d_in[2];
    const float* v_feat = (const float*)d_in[3];
    const int* fsrc = (const int*)d_in[4];
    const int* fdst = (const int*)d_in[5];
    const int* bsrc = (const int*)d_in[6];
    const int* bdst = (const int*)d_in[7];
    const float* We  = (const float*)d_in[8];
    const float* be  = (const float*)d_in[9];
    const float* Wul = (const float*)d_in[10];
    const float* bul = (const float*)d_in[11];
    const float* Wvl = (const float*)d_in[12];
    const float* bvl = (const float*)d_in[13];
    const float* Wau = (const float*)d_in[14];
    const float* bau = (const float*)d_in[15];
    const float* Wav = (const float*)d_in[16];
    const float* bav = (const float*)d_in[17];
    const float* Wwu = (const float*)d_in[18];
    const float* bwu = (const float*)d_in[19];
    const float* Wwv = (const float*)d_in[20];
    const float* bwv = (const float*)d_in[21];
    const float* WVu = (const float*)d_in[22];
    const float* bVu = (const float*)d_in[23];
    const float* WVv = (const float*)d_in[24];
    const float* bVv = (const float*)d_in[25];

    int EF = in_sizes[0] / 64;
    int EB = in_sizes[1] / 64;
    int NU = in_sizes[2] / 64;
    int NV = in_sizes[3] / 64;

    float* out = (float*)d_out;
    float* hf = out;
    float* hb = hf + (size_t)EF * 64;
    float* hu = hb + (size_t)EB * 64;
    float* hv = hu + (size_t)NU * 64;

    char* wp = (char*)d_ws;
    auto alloc = [&](size_t bytes) { char* p = wp; wp += (bytes + 255) & ~(size_t)255; return p; };
    unsigned short* he_u  = (unsigned short*)alloc((size_t)NU * 64 * 2);
    unsigned short* he_v  = (unsigned short*)alloc((size_t)NV * 64 * 2);
    unsigned* att_u = (unsigned*)alloc((size_t)NU * 64 * 4);
    unsigned* att_v = (unsigned*)alloc((size_t)NV * 64 * 4);
    unsigned short* ubf_u = (unsigned short*)alloc((size_t)NU * 64 * 2);
    unsigned short* ubf_v = (unsigned short*)alloc((size_t)NV * 64 * 2);
    float* proj_u = (float*)alloc((size_t)NU * 32 * 4);
    float* proj_v = (float*)alloc((size_t)NV * 32 * 4);
    float* agg_u  = (float*)alloc((size_t)NU * 32 * 4);
    float* agg_v  = (float*)alloc((size_t)NV * 32 * 4);
    float* ws_u   = (float*)alloc((size_t)NU * 4);
    float* ws_v   = (float*)alloc((size_t)NV * 4);
    unsigned short* WeXf = (unsigned short*)alloc(96 * 64 * 2);
    unsigned short* WeXb = (unsigned short*)alloc(96 * 64 * 2);
    unsigned short* WuT  = (unsigned short*)alloc(256 * 64 * 2);
    unsigned short* WvT  = (unsigned short*)alloc(256 * 64 * 2);
    float* bcu = (float*)alloc(224 * 4);
    float* bcv = (float*)alloc(224 * 4);

    prep_kernel<<<64, 256, 0, stream>>>(We, Wul, Wau, WVu, Wvl, Wav, WVv, Wwu, Wwv,
                                        bul, bau, bVu, bvl, bav, bVv,
                                        WeXf, WeXb, WuT, WvT, bcu, bcv);

    node_pre_kernel<<<(NU + 63) / 64, 256, 0, stream>>>(u_feat, NU, WuT, bcu,
                                                        he_u, att_u, ubf_u, hu, proj_u, agg_u, ws_u);
    node_pre_kernel<<<(NV + 63) / 64, 256, 0, stream>>>(v_feat, NV, WvT, bcv,
                                                        he_v, att_v, ubf_v, hv, proj_v, agg_v, ws_v);

    edge_kernel<<<(EF + 63) / 64, 256, 0, stream>>>(f_feat, EF, fsrc, fdst, ubf_u, proj_u,
                                                    he_u, he_v, att_v, WeXf, be, hf, agg_v, ws_v);
    edge_kernel<<<(EB + 63) / 64, 256, 0, stream>>>(b_feat, EB, bsrc, bdst, ubf_v, proj_v,
                                                    he_v, he_u, att_u, WeXb, be, hb, agg_u, ws_u);

    finalize_kernel<<<(NU * 32 + 255) / 256, 256, 0, stream>>>(agg_u, ws_u, NU, bwu, hu);
    finalize_kernel<<<(NV * 32 + 255) / 256, 256, 0, stream>>>(agg_v, ws_v, NV, bwv, hv);
}